// Round 4
// baseline (1147.578 us; speedup 1.0000x reference)
//
#include <hip/hip_runtime.h>

static constexpr int BLK = 256;
static constexpr int CHUNK = 8192;   // edges per hist/bin block
static constexpr int BSHIFT = 7;     // 128 dst-nodes per bucket
static constexpr int BNODES = 128;
static constexpr int MAXNB = 1024;

// ---------------- bucket build ----------------

__global__ __launch_bounds__(BLK) void k_hist(const int* __restrict__ dst, int* __restrict__ ghist,
                                              int e, int NB, int NBLK) {
    __shared__ int h[MAXNB];
    for (int i = threadIdx.x; i < NB; i += BLK) h[i] = 0;
    __syncthreads();
    int base = blockIdx.x * CHUNK;
    int lim = min(e - base, CHUNK);
    for (int r = threadIdx.x; r < lim; r += BLK) atomicAdd(&h[dst[base + r] >> BSHIFT], 1);
    __syncthreads();
    for (int b = threadIdx.x; b < NB; b += BLK) ghist[b * NBLK + blockIdx.x] = h[b];
}

__global__ void k_scan1(const int* __restrict__ in, int* __restrict__ excl,
                        int* __restrict__ partials, int n) {
    __shared__ int s[BLK];
    int i = blockIdx.x * BLK + threadIdx.x;
    int v = (i < n) ? in[i] : 0;
    s[threadIdx.x] = v;
    __syncthreads();
    for (int off = 1; off < BLK; off <<= 1) {
        int t = ((int)threadIdx.x >= off) ? s[threadIdx.x - off] : 0;
        __syncthreads();
        s[threadIdx.x] += t;
        __syncthreads();
    }
    if (i < n) excl[i] = s[threadIdx.x] - v;
    if (threadIdx.x == BLK - 1) partials[blockIdx.x] = s[BLK - 1];
}

__global__ void k_scan2(int* __restrict__ partials, int P) {
    __shared__ int s[1024];
    int carry = 0;
    for (int base = 0; base < P; base += 1024) {
        int i = base + (int)threadIdx.x;
        int v = (i < P) ? partials[i] : 0;
        s[threadIdx.x] = v;
        __syncthreads();
        for (int off = 1; off < 1024; off <<= 1) {
            int t = ((int)threadIdx.x >= off) ? s[threadIdx.x - off] : 0;
            __syncthreads();
            s[threadIdx.x] += t;
            __syncthreads();
        }
        if (i < P) partials[i] = carry + s[threadIdx.x] - v;
        carry += s[1023];
        __syncthreads();
    }
}

__global__ void k_scan3(int* __restrict__ excl, const int* __restrict__ partials, int n) {
    int i = blockIdx.x * BLK + threadIdx.x;
    if (i < n) excl[i] += partials[blockIdx.x];
}

// LDS-staged multisplit: bin edges by dst bucket, coalesced run writes.
// key = src | (dst&127)<<20   (requires n < 2^20)
__global__ __launch_bounds__(BLK) void k_bin(const int* __restrict__ src, const int* __restrict__ dst,
                                             const int* __restrict__ goff, unsigned int* __restrict__ keys,
                                             int e, int NB, int NBLK) {
    __shared__ int hcur[MAXNB];
    __shared__ int sstart[MAXNB + 1];
    __shared__ unsigned int stage[CHUNK];
    for (int i = threadIdx.x; i < NB; i += BLK) hcur[i] = 0;
    __syncthreads();
    int base = blockIdx.x * CHUNK;
    int lim = min(e - base, CHUNK);
    for (int r = threadIdx.x; r < lim; r += BLK) atomicAdd(&hcur[dst[base + r] >> BSHIFT], 1);
    __syncthreads();
    // inclusive scan of hist into sstart
    for (int i = threadIdx.x; i < MAXNB; i += BLK) sstart[i] = (i < NB) ? hcur[i] : 0;
    __syncthreads();
    for (int off = 1; off < MAXNB; off <<= 1) {
        int tv[MAXNB / BLK];
#pragma unroll
        for (int j = 0; j < MAXNB / BLK; ++j) {
            int i = (int)threadIdx.x + j * BLK;
            tv[j] = (i >= off) ? sstart[i - off] : 0;
        }
        __syncthreads();
#pragma unroll
        for (int j = 0; j < MAXNB / BLK; ++j) sstart[(int)threadIdx.x + j * BLK] += tv[j];
        __syncthreads();
    }
    // convert to exclusive; init cursors
    int ex[MAXNB / BLK];
#pragma unroll
    for (int j = 0; j < MAXNB / BLK; ++j) {
        int i = (int)threadIdx.x + j * BLK;
        ex[j] = sstart[i] - ((i < NB) ? hcur[i] : 0);
    }
    __syncthreads();
#pragma unroll
    for (int j = 0; j < MAXNB / BLK; ++j) {
        int i = (int)threadIdx.x + j * BLK;
        sstart[i] = ex[j];
        if (i < NB) hcur[i] = ex[j];
    }
    if (threadIdx.x == 0) sstart[NB] = lim;
    __syncthreads();
    // place into LDS stage
    for (int r = threadIdx.x; r < lim; r += BLK) {
        int s = src[base + r], d = dst[base + r];
        int b = d >> BSHIFT;
        int pos = atomicAdd(&hcur[b], 1);
        stage[pos] = (unsigned)s | ((unsigned)(d & (BNODES - 1)) << 20);
    }
    __syncthreads();
    // coalesced-run write-out (binary search bucket of j)
    for (int j = threadIdx.x; j < lim; j += BLK) {
        int lo = 0, hi = NB;
        while (hi - lo > 1) {
            int mid = (lo + hi) >> 1;
            if (sstart[mid] <= j) lo = mid; else hi = mid;
        }
        keys[goff[lo * NBLK + blockIdx.x] + (j - sstart[lo])] = stage[j];
    }
}

// per-bucket degree -> dis = rsqrt(1 + indeg)
__global__ __launch_bounds__(BLK) void k_dis2(const unsigned int* __restrict__ keys,
                                              const int* __restrict__ goff, float* __restrict__ dis,
                                              int n, int NB, int NBLK, int e) {
    __shared__ int cnt[BNODES];
    int b = blockIdx.x;
    if (threadIdx.x < BNODES) cnt[threadIdx.x] = 1;
    __syncthreads();
    int start = goff[b * NBLK];
    int end = (b + 1 < NB) ? goff[(b + 1) * NBLK] : e;
    for (int k = start + (int)threadIdx.x; k < end; k += BLK) atomicAdd(&cnt[keys[k] >> 20], 1);
    __syncthreads();
    if (threadIdx.x < BNODES) {
        int d = b * BNODES + threadIdx.x;
        if (d < n) dis[d] = rsqrtf((float)cnt[threadIdx.x]);
    }
}

// ---------------- dense transform ----------------

// out[n,COUT] = in @ W (+bias) (relu?) (*dis[node]?)
template <int CIN, int COUT, bool BIAS, bool RELU_OUT, bool SCALE_OUT>
__global__ void k_transform(const float* __restrict__ in, const float* __restrict__ W,
                            const float* __restrict__ bias, const float* __restrict__ dis,
                            float* __restrict__ out, int n) {
    int t = blockIdx.x * BLK + threadIdx.x;
    int node = t / COUT, c = t % COUT;
    if (node >= n) return;
    const float* row = in + (size_t)node * CIN;
    float acc = BIAS ? bias[c] : 0.0f;
#pragma unroll
    for (int k = 0; k < CIN; ++k) acc = fmaf(row[k], W[k * COUT + c], acc);
    if (RELU_OUT) acc = fmaxf(acc, 0.0f);
    if (SCALE_OUT) acc *= dis[node];
    out[t] = acc;
}

// ---------------- bucket aggregation ----------------
// in = pre-scaled z-hat; acc[d] = in[d] + sum_{edges into d} in[s]
// WMODE 0: out = dis*relu(bias + dis*acc)   (layer-1 output, pre-scaled for L2)
// WMODE 1: out = dis*acc                    (layer-2 aggregate)
// WMODE 2: out = bias + dis*acc             (layer-3 output h3)
template <int WMODE>
__global__ __launch_bounds__(BLK) void k_bagg(const float* __restrict__ in, const float* __restrict__ dis,
                                              const float* __restrict__ bias,
                                              const unsigned int* __restrict__ keys,
                                              const int* __restrict__ goff, float* __restrict__ out,
                                              int n, int NB, int NBLK, int e) {
    __shared__ float acc[BNODES * 17];
    __shared__ float disl[BNODES];
    int b = blockIdx.x;
    int start = goff[b * NBLK];
    int end = (b + 1 < NB) ? goff[(b + 1) * NBLK] : e;
    if (threadIdx.x < BNODES) {
        int d = b * BNODES + threadIdx.x;
        disl[threadIdx.x] = (d < n) ? dis[d] : 0.0f;
    }
    for (int idx = threadIdx.x; idx < BNODES * 16; idx += BLK) {
        int dlo = idx >> 4, c = idx & 15;
        int d = b * BNODES + dlo;
        acc[dlo * 17 + c] = (d < n) ? in[(size_t)d * 16 + c] : 0.0f;  // self-loop term
    }
    __syncthreads();
    int gid = threadIdx.x >> 4, c = threadIdx.x & 15;  // 16 lane-groups x 16 channels
    int k = start + gid;
    for (; k + 16 < end; k += 32) {
        unsigned key0 = keys[k], key1 = keys[k + 16];
        int s0 = key0 & 0xFFFFF, dl0 = key0 >> 20;
        int s1 = key1 & 0xFFFFF, dl1 = key1 >> 20;
        float u0 = in[(size_t)s0 * 16 + c];
        float u1 = in[(size_t)s1 * 16 + c];
        atomicAdd(&acc[dl0 * 17 + c], u0);
        atomicAdd(&acc[dl1 * 17 + c], u1);
    }
    if (k < end) {
        unsigned key0 = keys[k];
        int s0 = key0 & 0xFFFFF, dl0 = key0 >> 20;
        atomicAdd(&acc[dl0 * 17 + c], in[(size_t)s0 * 16 + c]);
    }
    __syncthreads();
    for (int idx = threadIdx.x; idx < BNODES * 16; idx += BLK) {
        int dlo = idx >> 4, cc = idx & 15;
        int d = b * BNODES + dlo;
        if (d >= n) continue;
        float a = acc[dlo * 17 + cc] * disl[dlo];
        float r;
        if (WMODE == 0)      r = disl[dlo] * fmaxf(bias[cc] + a, 0.0f);
        else if (WMODE == 1) r = a;
        else                 r = bias[cc] + a;
        out[(size_t)d * 16 + cc] = r;
    }
}

// ---------------- output ----------------

__global__ void k_zero(float* __restrict__ out) { out[0] = 0.0f; }

__global__ void k_final(const float* __restrict__ h, const float* __restrict__ Wfc,
                        const float* __restrict__ bfc, float* __restrict__ out, int n,
                        float inv_n) {
    int i = blockIdx.x * BLK + threadIdx.x;
    float v = 0.0f;
    if (i < n) {
        float acc = bfc[0];
        const float* row = h + (size_t)i * 16;
#pragma unroll
        for (int c = 0; c < 16; ++c) acc = fmaf(fmaxf(row[c], 0.0f), Wfc[c], acc);
        v = acc;
    }
#pragma unroll
    for (int off = 32; off > 0; off >>= 1) v += __shfl_down(v, off);
    __shared__ float sw[BLK / 64];
    int wid = threadIdx.x >> 6;
    if ((threadIdx.x & 63) == 0) sw[wid] = v;
    __syncthreads();
    if (threadIdx.x == 0) {
        float t = 0.0f;
#pragma unroll
        for (int w = 0; w < BLK / 64; ++w) t += sw[w];
        atomicAdd(out, t * inv_n);
    }
}

// ---------------- fallback (atomic scatter) ----------------

__global__ void k_deg_init(float* __restrict__ deg, int n) {
    int i = blockIdx.x * BLK + threadIdx.x;
    if (i < n) deg[i] = 1.0f;
}
__global__ void k_deg_count(const int* __restrict__ dst, float* __restrict__ deg, int e) {
    int i = blockIdx.x * BLK + threadIdx.x;
    if (i < e) atomicAdd(&deg[dst[i]], 1.0f);
}
__global__ void k_deg_rsqrt(float* __restrict__ deg, int n) {
    int i = blockIdx.x * BLK + threadIdx.x;
    if (i < n) deg[i] = rsqrtf(deg[i]);
}
template <int C, bool RELU_IN, bool BIAS>
__global__ void k_selfloop(const float* __restrict__ h, const float* __restrict__ dis,
                           const float* __restrict__ b, float* __restrict__ agg, int n) {
    int t = blockIdx.x * BLK + threadIdx.x;
    int node = t / C, c = t % C;
    if (node >= n) return;
    float w = dis[node];
    float v = h[t];
    if (RELU_IN) v = fmaxf(v, 0.0f);
    agg[t] = (BIAS ? b[c] : 0.0f) + v * w * w;
}
template <int C, bool RELU_IN>
__global__ void k_scatter(const int* __restrict__ src, const int* __restrict__ dst,
                          const float* __restrict__ h, const float* __restrict__ dis,
                          float* __restrict__ agg, int e) {
    int t = blockIdx.x * BLK + threadIdx.x;
    int edge = t / C, c = t % C;
    if (edge >= e) return;
    int s = src[edge], d = dst[edge];
    float w = dis[s] * dis[d];
    float v = h[(size_t)s * C + c];
    if (RELU_IN) v = fmaxf(v, 0.0f);
    atomicAdd(&agg[(size_t)d * C + c], v * w);
}

// ---------------- launch ----------------

extern "C" void kernel_launch(void* const* d_in, const int* in_sizes, int n_in,
                              void* d_out, int out_size, void* d_ws, size_t ws_size,
                              hipStream_t stream) {
    const float* x   = (const float*)d_in[0];
    const int* ei    = (const int*)d_in[1];   // integer inputs delivered as int32
    const float* W1  = (const float*)d_in[2];
    const float* b1  = (const float*)d_in[3];
    const float* W2  = (const float*)d_in[4];
    const float* b2  = (const float*)d_in[5];
    const float* W3  = (const float*)d_in[6];
    const float* b3  = (const float*)d_in[7];
    const float* Wfc = (const float*)d_in[8];
    const float* bfc = (const float*)d_in[9];
    float* out = (float*)d_out;

    const int n = in_sizes[0] / 32;
    const int e = in_sizes[1] / 2;
    const int* src = ei;
    const int* dst = ei + e;

    auto g1 = [](long long work) { return dim3((unsigned)((work + BLK - 1) / BLK)); };

    const int NB   = (n + BNODES - 1) >> BSHIFT;        // dst buckets
    const int NBLK = (e + CHUNK - 1) / CHUNK;           // hist/bin blocks
    const long long L = (long long)NB * NBLK;           // histogram size
    const int P = (int)((L + BLK - 1) / BLK);           // scan partials

    auto align_up = [](size_t v) { return (v + 255) & ~(size_t)255; };
    size_t off = 0;
    auto carve = [&](size_t bytes) { size_t o = off; off += align_up(bytes); return o; };
    char* base = (char*)d_ws;
    size_t o_dis   = carve((size_t)n * 4);
    size_t o_ghist = carve((size_t)L * 4);
    size_t o_goff  = carve((size_t)L * 4);
    size_t o_part  = carve(((size_t)P + 1) * 4);
    size_t o_A     = carve((size_t)n * 16 * 4);
    size_t o_B     = carve((size_t)n * 32 * 4);
    size_t o_keys  = carve((size_t)e * 4);
    bool ok = (off <= ws_size) && (NB <= MAXNB) && (n < (1 << 20));

    if (ok) {
        float* dis  = (float*)(base + o_dis);
        int* ghist  = (int*)(base + o_ghist);
        int* goff   = (int*)(base + o_goff);
        int* part   = (int*)(base + o_part);
        float* A    = (float*)(base + o_A);
        float* B    = (float*)(base + o_B);
        unsigned int* keys = (unsigned int*)(base + o_keys);

        // build: hist -> scan -> bin -> degrees
        k_hist<<<dim3(NBLK), BLK, 0, stream>>>(dst, ghist, e, NB, NBLK);
        k_scan1<<<g1(L), BLK, 0, stream>>>(ghist, goff, part, (int)L);
        k_scan2<<<1, 1024, 0, stream>>>(part, P);
        k_scan3<<<g1(L), BLK, 0, stream>>>(goff, part, (int)L);
        k_bin<<<dim3(NBLK), BLK, 0, stream>>>(src, dst, goff, keys, e, NB, NBLK);
        k_dis2<<<dim3(NB), BLK, 0, stream>>>(keys, goff, dis, n, NB, NBLK, e);

        // L1: z1hat = (x@W1)*dis ; B = dis*relu(b1 + dis*sum(z1hat))
        k_transform<32, 16, false, false, true><<<g1((long long)n * 16), BLK, 0, stream>>>(x, W1, nullptr, dis, A, n);
        k_bagg<0><<<dim3(NB), BLK, 0, stream>>>(A, dis, b1, keys, goff, B, n, NB, NBLK, e);

        // L2: A = dis*sum(B) ; B = relu(A@W2 + b2)
        k_bagg<1><<<dim3(NB), BLK, 0, stream>>>(B, dis, nullptr, keys, goff, A, n, NB, NBLK, e);
        k_transform<16, 32, true, true, false><<<g1((long long)n * 32), BLK, 0, stream>>>(A, W2, b2, nullptr, B, n);

        // L3: z3hat = (B@W3)*dis ; B = b3 + dis*sum(z3hat)
        k_transform<32, 16, false, false, true><<<g1((long long)n * 16), BLK, 0, stream>>>(B, W3, nullptr, dis, A, n);
        k_bagg<2><<<dim3(NB), BLK, 0, stream>>>(A, dis, b3, keys, goff, B, n, NB, NBLK, e);

        k_zero<<<1, 1, 0, stream>>>(out);
        k_final<<<g1(n), BLK, 0, stream>>>(B, Wfc, bfc, out, n, 1.0f / (float)n);
    } else {
        // fallback: atomic scatter path
        float* dis = (float*)d_ws;
        float* A = dis + (((size_t)n + 255) & ~(size_t)255);
        float* B = A + (size_t)n * 32;

        k_deg_init<<<g1(n), BLK, 0, stream>>>(dis, n);
        k_deg_count<<<g1(e), BLK, 0, stream>>>(dst, dis, e);
        k_deg_rsqrt<<<g1(n), BLK, 0, stream>>>(dis, n);

        k_transform<32, 16, false, false, false><<<g1((long long)n * 16), BLK, 0, stream>>>(x, W1, nullptr, nullptr, A, n);
        k_selfloop<16, false, true><<<g1((long long)n * 16), BLK, 0, stream>>>(A, dis, b1, B, n);
        k_scatter<16, false><<<g1((long long)e * 16), BLK, 0, stream>>>(src, dst, A, dis, B, e);

        k_selfloop<16, true, false><<<g1((long long)n * 16), BLK, 0, stream>>>(B, dis, nullptr, A, n);
        k_scatter<16, true><<<g1((long long)e * 16), BLK, 0, stream>>>(src, dst, B, dis, A, e);
        k_transform<16, 32, true, true, false><<<g1((long long)n * 32), BLK, 0, stream>>>(A, W2, b2, nullptr, B, n);

        k_transform<32, 16, false, false, false><<<g1((long long)n * 16), BLK, 0, stream>>>(B, W3, nullptr, nullptr, A, n);
        k_selfloop<16, false, true><<<g1((long long)n * 16), BLK, 0, stream>>>(A, dis, b3, B, n);
        k_scatter<16, false><<<g1((long long)e * 16), BLK, 0, stream>>>(src, dst, A, dis, B, e);

        k_zero<<<1, 1, 0, stream>>>(out);
        k_final<<<g1(n), BLK, 0, stream>>>(B, Wfc, bfc, out, n, 1.0f / (float)n);
    }
}

// Round 5
// 278.468 us; speedup vs baseline: 4.1210x; 4.1210x over previous
//
#include <hip/hip_runtime.h>

static constexpr int BLK = 256;
static constexpr int CHUNK = 8192;   // edges per hist/bin block
static constexpr int BSHIFT = 7;     // 128 dst-nodes per bucket
static constexpr int BNODES = 128;
static constexpr int MAXNB = 1024;

// ---------------- bucket build ----------------

__global__ __launch_bounds__(BLK) void k_hist(const int* __restrict__ dst, int* __restrict__ ghist,
                                              int e, int NB, int NBLK) {
    __shared__ int h[MAXNB];
    for (int i = threadIdx.x; i < NB; i += BLK) h[i] = 0;
    __syncthreads();
    int base = blockIdx.x * CHUNK;
    int lim = min(e - base, CHUNK);
    for (int r = threadIdx.x; r < lim; r += BLK) atomicAdd(&h[dst[base + r] >> BSHIFT], 1);
    __syncthreads();
    for (int b = threadIdx.x; b < NB; b += BLK) ghist[b * NBLK + blockIdx.x] = h[b];
}

__global__ void k_scan1(const int* __restrict__ in, int* __restrict__ excl,
                        int* __restrict__ partials, int n) {
    __shared__ int s[BLK];
    int i = blockIdx.x * BLK + threadIdx.x;
    int v = (i < n) ? in[i] : 0;
    s[threadIdx.x] = v;
    __syncthreads();
    for (int off = 1; off < BLK; off <<= 1) {
        int t = ((int)threadIdx.x >= off) ? s[threadIdx.x - off] : 0;
        __syncthreads();
        s[threadIdx.x] += t;
        __syncthreads();
    }
    if (i < n) excl[i] = s[threadIdx.x] - v;
    if (threadIdx.x == BLK - 1) partials[blockIdx.x] = s[BLK - 1];
}

__global__ void k_scan2(int* __restrict__ partials, int P) {
    __shared__ int s[1024];
    int carry = 0;
    for (int base = 0; base < P; base += 1024) {
        int i = base + (int)threadIdx.x;
        int v = (i < P) ? partials[i] : 0;
        s[threadIdx.x] = v;
        __syncthreads();
        for (int off = 1; off < 1024; off <<= 1) {
            int t = ((int)threadIdx.x >= off) ? s[threadIdx.x - off] : 0;
            __syncthreads();
            s[threadIdx.x] += t;
            __syncthreads();
        }
        if (i < P) partials[i] = carry + s[threadIdx.x] - v;
        carry += s[1023];
        __syncthreads();
    }
}

__global__ void k_scan3(int* __restrict__ excl, const int* __restrict__ partials, int n) {
    int i = blockIdx.x * BLK + threadIdx.x;
    if (i < n) excl[i] += partials[blockIdx.x];
}

// LDS-staged multisplit: bin edges by dst bucket, coalesced run writes.
// key = src | (dst&127)<<20   (requires n < 2^20)
__global__ __launch_bounds__(BLK) void k_bin(const int* __restrict__ src, const int* __restrict__ dst,
                                             const int* __restrict__ goff, unsigned int* __restrict__ keys,
                                             int e, int NB, int NBLK) {
    __shared__ int hcur[MAXNB];
    __shared__ int sstart[MAXNB + 1];
    __shared__ unsigned int stage[CHUNK];
    for (int i = threadIdx.x; i < NB; i += BLK) hcur[i] = 0;
    __syncthreads();
    int base = blockIdx.x * CHUNK;
    int lim = min(e - base, CHUNK);
    for (int r = threadIdx.x; r < lim; r += BLK) atomicAdd(&hcur[dst[base + r] >> BSHIFT], 1);
    __syncthreads();
    // inclusive scan of hist into sstart
    for (int i = threadIdx.x; i < MAXNB; i += BLK) sstart[i] = (i < NB) ? hcur[i] : 0;
    __syncthreads();
    for (int off = 1; off < MAXNB; off <<= 1) {
        int tv[MAXNB / BLK];
#pragma unroll
        for (int j = 0; j < MAXNB / BLK; ++j) {
            int i = (int)threadIdx.x + j * BLK;
            tv[j] = (i >= off) ? sstart[i - off] : 0;
        }
        __syncthreads();
#pragma unroll
        for (int j = 0; j < MAXNB / BLK; ++j) sstart[(int)threadIdx.x + j * BLK] += tv[j];
        __syncthreads();
    }
    // convert to exclusive; init cursors
    int ex[MAXNB / BLK];
#pragma unroll
    for (int j = 0; j < MAXNB / BLK; ++j) {
        int i = (int)threadIdx.x + j * BLK;
        ex[j] = sstart[i] - ((i < NB) ? hcur[i] : 0);
    }
    __syncthreads();
#pragma unroll
    for (int j = 0; j < MAXNB / BLK; ++j) {
        int i = (int)threadIdx.x + j * BLK;
        sstart[i] = ex[j];
        if (i < NB) hcur[i] = ex[j];
    }
    if (threadIdx.x == 0) sstart[NB] = lim;
    __syncthreads();
    // place into LDS stage
    for (int r = threadIdx.x; r < lim; r += BLK) {
        int s = src[base + r], d = dst[base + r];
        int b = d >> BSHIFT;
        int pos = atomicAdd(&hcur[b], 1);
        stage[pos] = (unsigned)s | ((unsigned)(d & (BNODES - 1)) << 20);
    }
    __syncthreads();
    // coalesced-run write-out (binary search bucket of j)
    for (int j = threadIdx.x; j < lim; j += BLK) {
        int lo = 0, hi = NB;
        while (hi - lo > 1) {
            int mid = (lo + hi) >> 1;
            if (sstart[mid] <= j) lo = mid; else hi = mid;
        }
        keys[goff[lo * NBLK + blockIdx.x] + (j - sstart[lo])] = stage[j];
    }
}

// per-bucket: node degrees -> dis + node offsets; counting-sort keys -> dst-sorted src CSR
__global__ __launch_bounds__(BLK) void k_sortb(const unsigned int* __restrict__ keys,
                                               const int* __restrict__ goff,
                                               unsigned int* __restrict__ sorted,
                                               int* __restrict__ node_off, float* __restrict__ dis,
                                               int n, int NB, int NBLK, int e) {
    __shared__ int cnt[BNODES];
    __shared__ int sc[BNODES];
    __shared__ int cur[BNODES];
    int b = blockIdx.x;
    int start = goff[b * NBLK];
    int end = (b + 1 < NB) ? goff[(b + 1) * NBLK] : e;
    if (threadIdx.x < BNODES) cnt[threadIdx.x] = 0;
    __syncthreads();
    for (int k = start + (int)threadIdx.x; k < end; k += BLK) atomicAdd(&cnt[keys[k] >> 20], 1);
    __syncthreads();
    if (threadIdx.x < BNODES) sc[threadIdx.x] = cnt[threadIdx.x];
    __syncthreads();
    for (int off = 1; off < BNODES; off <<= 1) {
        int v = ((int)threadIdx.x < BNODES && (int)threadIdx.x >= off) ? sc[threadIdx.x - off] : 0;
        __syncthreads();
        if ((int)threadIdx.x < BNODES) sc[threadIdx.x] += v;
        __syncthreads();
    }
    if ((int)threadIdx.x < BNODES) {
        int excl = sc[threadIdx.x] - cnt[threadIdx.x];
        cur[threadIdx.x] = start + excl;
        int d = b * BNODES + (int)threadIdx.x;
        if (d < n) {
            node_off[d] = start + excl;
            dis[d] = rsqrtf(1.0f + (float)cnt[threadIdx.x]);
        }
    }
    if (b == NB - 1 && threadIdx.x == 0) node_off[n] = e;
    __syncthreads();
    for (int k = start + (int)threadIdx.x; k < end; k += BLK) {
        unsigned key = keys[k];
        int pos = atomicAdd(&cur[key >> 20], 1);
        sorted[pos] = key & 0xFFFFFu;
    }
}

// ---------------- dense transform ----------------

// out[n,COUT] = in @ W (+bias) (relu?) (*dis[node]?)
template <int CIN, int COUT, bool BIAS, bool RELU_OUT, bool SCALE_OUT>
__global__ void k_transform(const float* __restrict__ in, const float* __restrict__ W,
                            const float* __restrict__ bias, const float* __restrict__ dis,
                            float* __restrict__ out, int n) {
    int t = blockIdx.x * BLK + threadIdx.x;
    int node = t / COUT, c = t % COUT;
    if (node >= n) return;
    const float* row = in + (size_t)node * CIN;
    float acc = BIAS ? bias[c] : 0.0f;
#pragma unroll
    for (int k = 0; k < CIN; ++k) acc = fmaf(row[k], W[k * COUT + c], acc);
    if (RELU_OUT) acc = fmaxf(acc, 0.0f);
    if (SCALE_OUT) acc *= dis[node];
    out[t] = acc;
}

// ---------------- gather aggregation (per node,channel; dst-sorted CSR) ----------------
// in = pre-scaled z-hat; acc = in[d] + sum_{s in N(d)} in[s]
// WMODE 0: out = dis*relu(bias + dis*acc)   (layer-1 output, pre-scaled for L2)
// WMODE 1: out = dis*acc                    (layer-2 aggregate)
// WMODE 2: out = bias + dis*acc             (layer-3 output h3)
template <int WMODE>
__global__ __launch_bounds__(BLK) void k_agg(const float* __restrict__ in, const float* __restrict__ dis,
                                             const float* __restrict__ bias,
                                             const unsigned int* __restrict__ sorted,
                                             const int* __restrict__ node_off,
                                             float* __restrict__ out, int n) {
    int t = blockIdx.x * BLK + threadIdx.x;
    int d = t >> 4, c = t & 15;
    if (d >= n) return;
    int k = node_off[d], end = node_off[d + 1];
    float a0 = in[((size_t)d << 4) + c], a1 = 0.0f, a2 = 0.0f, a3 = 0.0f;
    for (; k + 3 < end; k += 4) {
        int s0 = sorted[k], s1 = sorted[k + 1], s2 = sorted[k + 2], s3 = sorted[k + 3];
        a0 += in[((size_t)s0 << 4) + c];
        a1 += in[((size_t)s1 << 4) + c];
        a2 += in[((size_t)s2 << 4) + c];
        a3 += in[((size_t)s3 << 4) + c];
    }
    for (; k < end; ++k) a0 += in[((size_t)sorted[k] << 4) + c];
    float acc = (a0 + a1) + (a2 + a3);
    float sd = dis[d];
    float a = acc * sd;
    float r;
    if (WMODE == 0)      r = sd * fmaxf(bias[c] + a, 0.0f);
    else if (WMODE == 1) r = a;
    else                 r = bias[c] + a;
    out[((size_t)d << 4) + c] = r;
}

// ---------------- output ----------------

__global__ void k_zero(float* __restrict__ out) { out[0] = 0.0f; }

__global__ void k_final(const float* __restrict__ h, const float* __restrict__ Wfc,
                        const float* __restrict__ bfc, float* __restrict__ out, int n,
                        float inv_n) {
    int i = blockIdx.x * BLK + threadIdx.x;
    float v = 0.0f;
    if (i < n) {
        float acc = bfc[0];
        const float* row = h + (size_t)i * 16;
#pragma unroll
        for (int c = 0; c < 16; ++c) acc = fmaf(fmaxf(row[c], 0.0f), Wfc[c], acc);
        v = acc;
    }
#pragma unroll
    for (int off = 32; off > 0; off >>= 1) v += __shfl_down(v, off);
    __shared__ float sw[BLK / 64];
    int wid = threadIdx.x >> 6;
    if ((threadIdx.x & 63) == 0) sw[wid] = v;
    __syncthreads();
    if (threadIdx.x == 0) {
        float t = 0.0f;
#pragma unroll
        for (int w = 0; w < BLK / 64; ++w) t += sw[w];
        atomicAdd(out, t * inv_n);
    }
}

// ---------------- fallback (atomic scatter) ----------------

__global__ void k_deg_init(float* __restrict__ deg, int n) {
    int i = blockIdx.x * BLK + threadIdx.x;
    if (i < n) deg[i] = 1.0f;
}
__global__ void k_deg_count(const int* __restrict__ dst, float* __restrict__ deg, int e) {
    int i = blockIdx.x * BLK + threadIdx.x;
    if (i < e) atomicAdd(&deg[dst[i]], 1.0f);
}
__global__ void k_deg_rsqrt(float* __restrict__ deg, int n) {
    int i = blockIdx.x * BLK + threadIdx.x;
    if (i < n) deg[i] = rsqrtf(deg[i]);
}
template <int C, bool RELU_IN, bool BIAS>
__global__ void k_selfloop(const float* __restrict__ h, const float* __restrict__ dis,
                           const float* __restrict__ b, float* __restrict__ agg, int n) {
    int t = blockIdx.x * BLK + threadIdx.x;
    int node = t / C, c = t % C;
    if (node >= n) return;
    float w = dis[node];
    float v = h[t];
    if (RELU_IN) v = fmaxf(v, 0.0f);
    agg[t] = (BIAS ? b[c] : 0.0f) + v * w * w;
}
template <int C, bool RELU_IN>
__global__ void k_scatter(const int* __restrict__ src, const int* __restrict__ dst,
                          const float* __restrict__ h, const float* __restrict__ dis,
                          float* __restrict__ agg, int e) {
    int t = blockIdx.x * BLK + threadIdx.x;
    int edge = t / C, c = t % C;
    if (edge >= e) return;
    int s = src[edge], d = dst[edge];
    float w = dis[s] * dis[d];
    float v = h[(size_t)s * C + c];
    if (RELU_IN) v = fmaxf(v, 0.0f);
    atomicAdd(&agg[(size_t)d * C + c], v * w);
}

// ---------------- launch ----------------

extern "C" void kernel_launch(void* const* d_in, const int* in_sizes, int n_in,
                              void* d_out, int out_size, void* d_ws, size_t ws_size,
                              hipStream_t stream) {
    const float* x   = (const float*)d_in[0];
    const int* ei    = (const int*)d_in[1];   // integer inputs delivered as int32
    const float* W1  = (const float*)d_in[2];
    const float* b1  = (const float*)d_in[3];
    const float* W2  = (const float*)d_in[4];
    const float* b2  = (const float*)d_in[5];
    const float* W3  = (const float*)d_in[6];
    const float* b3  = (const float*)d_in[7];
    const float* Wfc = (const float*)d_in[8];
    const float* bfc = (const float*)d_in[9];
    float* out = (float*)d_out;

    const int n = in_sizes[0] / 32;
    const int e = in_sizes[1] / 2;
    const int* src = ei;
    const int* dst = ei + e;

    auto g1 = [](long long work) { return dim3((unsigned)((work + BLK - 1) / BLK)); };

    const int NB   = (n + BNODES - 1) >> BSHIFT;        // dst buckets
    const int NBLK = (e + CHUNK - 1) / CHUNK;           // hist/bin blocks
    const long long L = (long long)NB * NBLK;           // histogram size
    const int P = (int)((L + BLK - 1) / BLK);           // scan partials

    auto align_up = [](size_t v) { return (v + 255) & ~(size_t)255; };
    size_t off = 0;
    auto carve = [&](size_t bytes) { size_t o = off; off += align_up(bytes); return o; };
    char* base = (char*)d_ws;
    size_t o_dis   = carve((size_t)n * 4);
    size_t o_noff  = carve(((size_t)n + 1) * 4);
    size_t o_ghist = carve((size_t)L * 4);
    size_t o_goff  = carve((size_t)L * 4);
    size_t o_part  = carve(((size_t)P + 1) * 4);
    size_t o_A     = carve((size_t)n * 16 * 4);
    size_t o_B     = carve((size_t)n * 32 * 4);
    size_t o_keys  = carve((size_t)e * 4);
    size_t o_sort  = carve((size_t)e * 4);
    bool ok = (off <= ws_size) && (NB <= MAXNB) && (n < (1 << 20));

    if (ok) {
        float* dis  = (float*)(base + o_dis);
        int* noff   = (int*)(base + o_noff);
        int* ghist  = (int*)(base + o_ghist);
        int* goff   = (int*)(base + o_goff);
        int* part   = (int*)(base + o_part);
        float* A    = (float*)(base + o_A);
        float* B    = (float*)(base + o_B);
        unsigned int* keys   = (unsigned int*)(base + o_keys);
        unsigned int* sorted = (unsigned int*)(base + o_sort);

        // build: hist -> scan -> bin -> per-bucket sort (+ node offsets + dis)
        k_hist<<<dim3(NBLK), BLK, 0, stream>>>(dst, ghist, e, NB, NBLK);
        k_scan1<<<g1(L), BLK, 0, stream>>>(ghist, goff, part, (int)L);
        k_scan2<<<1, 1024, 0, stream>>>(part, P);
        k_scan3<<<g1(L), BLK, 0, stream>>>(goff, part, (int)L);
        k_bin<<<dim3(NBLK), BLK, 0, stream>>>(src, dst, goff, keys, e, NB, NBLK);
        k_sortb<<<dim3(NB), BLK, 0, stream>>>(keys, goff, sorted, noff, dis, n, NB, NBLK, e);

        // L1: z1hat = (x@W1)*dis ; B = dis*relu(b1 + dis*sum(z1hat))
        k_transform<32, 16, false, false, true><<<g1((long long)n * 16), BLK, 0, stream>>>(x, W1, nullptr, dis, A, n);
        k_agg<0><<<g1((long long)n * 16), BLK, 0, stream>>>(A, dis, b1, sorted, noff, B, n);

        // L2: A = dis*sum(B) ; B = relu(A@W2 + b2)
        k_agg<1><<<g1((long long)n * 16), BLK, 0, stream>>>(B, dis, nullptr, sorted, noff, A, n);
        k_transform<16, 32, true, true, false><<<g1((long long)n * 32), BLK, 0, stream>>>(A, W2, b2, nullptr, B, n);

        // L3: z3hat = (B@W3)*dis ; B = b3 + dis*sum(z3hat)
        k_transform<32, 16, false, false, true><<<g1((long long)n * 16), BLK, 0, stream>>>(B, W3, nullptr, dis, A, n);
        k_agg<2><<<g1((long long)n * 16), BLK, 0, stream>>>(A, dis, b3, sorted, noff, B, n);

        k_zero<<<1, 1, 0, stream>>>(out);
        k_final<<<g1(n), BLK, 0, stream>>>(B, Wfc, bfc, out, n, 1.0f / (float)n);
    } else {
        // fallback: atomic scatter path
        float* dis = (float*)d_ws;
        float* A = dis + (((size_t)n + 255) & ~(size_t)255);
        float* B = A + (size_t)n * 32;

        k_deg_init<<<g1(n), BLK, 0, stream>>>(dis, n);
        k_deg_count<<<g1(e), BLK, 0, stream>>>(dst, dis, e);
        k_deg_rsqrt<<<g1(n), BLK, 0, stream>>>(dis, n);

        k_transform<32, 16, false, false, false><<<g1((long long)n * 16), BLK, 0, stream>>>(x, W1, nullptr, nullptr, A, n);
        k_selfloop<16, false, true><<<g1((long long)n * 16), BLK, 0, stream>>>(A, dis, b1, B, n);
        k_scatter<16, false><<<g1((long long)e * 16), BLK, 0, stream>>>(src, dst, A, dis, B, e);

        k_selfloop<16, true, false><<<g1((long long)n * 16), BLK, 0, stream>>>(B, dis, nullptr, A, n);
        k_scatter<16, true><<<g1((long long)e * 16), BLK, 0, stream>>>(src, dst, B, dis, A, e);
        k_transform<16, 32, true, true, false><<<g1((long long)n * 32), BLK, 0, stream>>>(A, W2, b2, nullptr, B, n);

        k_transform<32, 16, false, false, false><<<g1((long long)n * 16), BLK, 0, stream>>>(B, W3, nullptr, nullptr, A, n);
        k_selfloop<16, false, true><<<g1((long long)n * 16), BLK, 0, stream>>>(A, dis, b3, B, n);
        k_scatter<16, false><<<g1((long long)e * 16), BLK, 0, stream>>>(src, dst, A, dis, B, e);

        k_zero<<<1, 1, 0, stream>>>(out);
        k_final<<<g1(n), BLK, 0, stream>>>(B, Wfc, bfc, out, n, 1.0f / (float)n);
    }
}